// Round 6
// baseline (645.051 us; speedup 1.0000x reference)
//
#include <hip/hip_runtime.h>
#include <hip/hip_bf16.h>

#define NPTS   32768
#define EEDGES 1048576
#define PTSC   1024
#define NCLOUD 32
#define ADIM   132              // per-cloud stride: 128 x + 3 pos + pad
#define MROW   (NCLOUD * ADIM)  // 4224
#define NBLK   256              // contract partial blocks
#define CHUNK  (NPTS / NBLK)    // 128
#define FXSCALE 16777216.0f     // 2^24

// ---------------- weight transpose prep: dst[c*R + r] = src[r*C + c] ----------------
__global__ __launch_bounds__(256) void prep_kernel(
    const float* __restrict__ w2, const float* __restrict__ w3,
    const float* __restrict__ locw, const float* __restrict__ globw,
    const float* __restrict__ d1w, const float* __restrict__ d2w,
    const float* __restrict__ d3w,
    float* __restrict__ w2T, float* __restrict__ w3T,
    float* __restrict__ locT, float* __restrict__ globT,
    float* __restrict__ d1T, float* __restrict__ d2T, float* __restrict__ d3T) {
  int idx = blockIdx.x * 256 + threadIdx.x;
  const float* src; float* dst; int R, C;
  if (idx < 4096)        { src = w2;   dst = w2T;   R = 64;  C = 64;  }
  else if (idx < 12288)  { src = w3;   dst = w3T;   R = 128; C = 64;  idx -= 4096; }
  else if (idx < 45824)  { src = locw; dst = locT;  R = 256; C = 131; idx -= 12288; }
  else if (idx < 144128) { src = globw;dst = globT; R = 384; C = 256; idx -= 45824; }
  else if (idx < 242432) { src = d1w;  dst = d1T;   R = 256; C = 384; idx -= 144128; }
  else if (idx < 275200) { src = d2w;  dst = d2T;   R = 128; C = 256; idx -= 242432; }
  else                   { src = d3w;  dst = d3T;   R = 16;  C = 128; idx -= 275200; }
  int c = idx / R, r = idx % R;
  dst[idx] = src[r * C + c];
}

__device__ __forceinline__ unsigned pack_bf16(float a, float b) {
  __hip_bfloat162 o;
  o.x = __float2bfloat16(a);
  o.y = __float2bfloat16(b);
  return *reinterpret_cast<unsigned*>(&o);
}

// ---------------- encoder: one point per thread, scalar-broadcast weights ----------------
__global__ __launch_bounds__(128) void enc_kernel(
    const float* __restrict__ pos,
    const float* __restrict__ w1, const float* __restrict__ b1,
    const float* __restrict__ w2T, const float* __restrict__ b2,
    const float* __restrict__ w3T, const float* __restrict__ b3,
    __hip_bfloat16* __restrict__ xb) {
  int i = blockIdx.x * 128 + threadIdx.x;
  float px = pos[i * 3 + 0], py = pos[i * 3 + 1], pz = pos[i * 3 + 2];

  float h1[64];
#pragma unroll
  for (int j = 0; j < 64; ++j)
    h1[j] = tanhf(w1[j * 3] * px + w1[j * 3 + 1] * py + w1[j * 3 + 2] * pz + b1[j]);

  float h2[64];
#pragma unroll
  for (int j = 0; j < 64; ++j) h2[j] = b2[j];
#pragma unroll
  for (int k = 0; k < 64; ++k) {
    float hk = h1[k];
#pragma unroll
    for (int j = 0; j < 64; ++j) h2[j] += w2T[k * 64 + j] * hk;
  }
#pragma unroll
  for (int j = 0; j < 64; ++j) h2[j] = tanhf(h2[j]);

  // layer 3 in two 64-row halves (keeps VGPR pressure bounded)
  for (int hf = 0; hf < 2; ++hf) {
    const float* wb = w3T + hf * 64;
    const float* bb = b3 + hf * 64;
    float acc[64];
#pragma unroll
    for (int r = 0; r < 64; ++r) acc[r] = bb[r];
#pragma unroll
    for (int k = 0; k < 64; ++k) {
      float hk = h2[k];
#pragma unroll
      for (int r = 0; r < 64; ++r) acc[r] += wb[k * 128 + r] * hk;
    }
    unsigned vals[32];
#pragma unroll
    for (int q = 0; q < 32; ++q)
      vals[q] = pack_bf16(tanhf(acc[2 * q]), tanhf(acc[2 * q + 1]));
    unsigned* op = reinterpret_cast<unsigned*>(xb + (size_t)i * 128 + hf * 64);
#pragma unroll
    for (int q = 0; q < 8; ++q) {
      uint4 v = make_uint4(vals[4 * q], vals[4 * q + 1], vals[4 * q + 2], vals[4 * q + 3]);
      *reinterpret_cast<uint4*>(op + 4 * q) = v;
    }
  }
}

// ---------------- degree histogram ----------------
__global__ __launch_bounds__(256) void hist_kernel(const int* __restrict__ ei,
                                                   int* __restrict__ cnt) {
  int t = blockIdx.x * 256 + threadIdx.x;
  const int4* d4 = reinterpret_cast<const int4*>(ei + EEDGES);
  int4 v = d4[t];
  atomicAdd(&cnt[v.x], 1);
  atomicAdd(&cnt[v.y], 1);
  atomicAdd(&cnt[v.z], 1);
  atomicAdd(&cnt[v.w], 1);
}

// invwi + self-loop diagonal store (runs after ai memset, before ascatter atomics)
__global__ __launch_bounds__(256) void invwi_kernel(const int* __restrict__ cnt,
                                                    int* __restrict__ invwi,
                                                    int* __restrict__ ai) {
  int i = blockIdx.x * 256 + threadIdx.x;
  if (i < NPTS) {
    int v = (int)rintf(FXSCALE / (float)(cnt[i] + 1));
    invwi[i] = v;
    ai[i * 32 + (i >> 10)] = v;   // self-loop contribution
  }
}

// ---------------- alpha scatter (edges only) ----------------
__global__ __launch_bounds__(256) void ascatter_kernel(const int* __restrict__ ei,
                                                       const int* __restrict__ invwi,
                                                       int* __restrict__ ai) {
  int e = blockIdx.x * 256 + threadIdx.x;
  int s = ei[e];
  int d = ei[e + EEDGES];
  atomicAdd(&ai[s * 32 + (d >> 10)], invwi[d]);
}

// ---------------- contraction: partial[b][c][dim] = sum_s alpha[s][c]*X[s][dim] ----------------
__global__ __launch_bounds__(256) void contract_kernel(
    const ushort* __restrict__ xu, const float* __restrict__ pos,
    const int* __restrict__ ai, float* __restrict__ partial) {
  int w = threadIdx.x >> 6, l = threadIdx.x & 63;
  int cw = w * 8;
  int s0 = blockIdx.x * CHUNK;
  int s1 = s0 + CHUNK;

  float a0[8] = {0,0,0,0,0,0,0,0};
  float a1[8] = {0,0,0,0,0,0,0,0};
  float a2[8] = {0,0,0,0,0,0,0,0};

#pragma unroll 2
  for (int s = s0; s < s1; ++s) {
    unsigned xr = *reinterpret_cast<const unsigned*>(xu + (size_t)s * 128 + 2 * l);
    float f0 = __uint_as_float(xr << 16);
    float f1 = __uint_as_float(xr & 0xffff0000u);
    float p  = (l < 3) ? pos[s * 3 + l] : 0.f;
    const int4* ar = reinterpret_cast<const int4*>(ai + (size_t)s * 32 + cw);
    int4 A0 = ar[0], A1 = ar[1];
    float af[8] = {(float)A0.x, (float)A0.y, (float)A0.z, (float)A0.w,
                   (float)A1.x, (float)A1.y, (float)A1.z, (float)A1.w};
#pragma unroll
    for (int cc = 0; cc < 8; ++cc) {
      a0[cc] += af[cc] * f0;
      a1[cc] += af[cc] * f1;
      a2[cc] += af[cc] * p;
    }
  }

  const float SC = 1.0f / FXSCALE;
  float* pb = partial + (size_t)blockIdx.x * MROW;
#pragma unroll
  for (int cc = 0; cc < 8; ++cc) {
    pb[(cw + cc) * ADIM + 2 * l]     = a0[cc] * SC;
    pb[(cw + cc) * ADIM + 2 * l + 1] = a1[cc] * SC;
    if (l < 3) pb[(cw + cc) * ADIM + 128 + l] = a2[cc] * SC;
  }
}

// ---------------- reduce: one wave per idx, shfl tree ----------------
__global__ __launch_bounds__(256) void reduce_kernel(const float* __restrict__ partial,
                                                     float* __restrict__ Macc) {
  int w = threadIdx.x >> 6, l = threadIdx.x & 63;
  int idx = blockIdx.x * 4 + w;
  if (idx >= MROW) return;
  float s = 0.f;
#pragma unroll
  for (int b = 0; b < NBLK; b += 64)
    s += partial[(size_t)(b + l) * MROW + idx];
  s += __shfl_xor(s, 32);
  s += __shfl_xor(s, 16);
  s += __shfl_xor(s, 8);
  s += __shfl_xor(s, 4);
  s += __shfl_xor(s, 2);
  s += __shfl_xor(s, 1);
  if (l == 0) Macc[idx] = s;
}

// ---------------- tail MLP (transposed weights, coalesced) ----------------
__global__ __launch_bounds__(256) void final_kernel(
    const float* __restrict__ Macc, const float* __restrict__ pos,
    const float* __restrict__ locT, const float* __restrict__ loc_b,
    const float* __restrict__ globT, const float* __restrict__ glob_b,
    const float* __restrict__ d1T, const float* __restrict__ d1b,
    const float* __restrict__ d2T, const float* __restrict__ d2b,
    const float* __restrict__ d3T, const float* __restrict__ d3b,
    float* __restrict__ out) {
  int c = blockIdx.x, t = threadIdx.x;
  __shared__ float red[3][256];
  __shared__ float m[131];
  __shared__ float tt[256];
  __shared__ float u[384];
  __shared__ float a[256];
  __shared__ float bv[128];

  float s0 = 0.f, s1 = 0.f, s2 = 0.f;
  for (int i = t; i < PTSC; i += 256) {
    const float* pr = pos + ((size_t)c * PTSC + i) * 3;
    s0 += pr[0]; s1 += pr[1]; s2 += pr[2];
  }
  red[0][t] = s0; red[1][t] = s1; red[2][t] = s2;
  __syncthreads();
  for (int off = 128; off > 0; off >>= 1) {
    if (t < off) {
      red[0][t] += red[0][t + off];
      red[1][t] += red[1][t + off];
      red[2][t] += red[2][t + off];
    }
    __syncthreads();
  }

  if (t < 128)      m[t] = Macc[c * ADIM + t] * (1.0f / (float)PTSC);
  else if (t < 131) m[t] = (Macc[c * ADIM + t] - red[t - 128][0]) * (1.0f / (float)PTSC);
  __syncthreads();

  {
    float acc = loc_b[t];
    for (int k = 0; k < 131; ++k) acc += locT[k * 256 + t] * m[k];
    tt[t] = acc;
  }
  __syncthreads();

  for (int j = t; j < 384; j += 256) {
    float acc = glob_b[j];
    for (int k = 0; k < 256; ++k) acc += globT[k * 384 + j] * tt[k];
    u[j] = acc;
  }
  __syncthreads();

  {
    float acc = d1b[t];
    for (int k = 0; k < 384; ++k) acc += d1T[k * 256 + t] * u[k];
    a[t] = tanhf(acc);
  }
  __syncthreads();

  if (t < 128) {
    float acc = d2b[t];
    for (int k = 0; k < 256; ++k) acc += d2T[k * 128 + t] * a[k];
    bv[t] = tanhf(acc);
  }
  __syncthreads();

  if (t < 16) {
    float acc = d3b[t];
    for (int k = 0; k < 128; ++k) acc += d3T[k * 16 + t] * bv[k];
    out[c * 16 + t] = acc;
  }
}

extern "C" void kernel_launch(void* const* d_in, const int* in_sizes, int n_in,
                              void* d_out, int out_size, void* d_ws, size_t ws_size,
                              hipStream_t stream) {
  const float* pos    = (const float*)d_in[0];
  const int*   ei     = (const int*)d_in[1];
  const float* enc1_w = (const float*)d_in[2];
  const float* enc1_b = (const float*)d_in[3];
  const float* enc2_w = (const float*)d_in[4];
  const float* enc2_b = (const float*)d_in[5];
  const float* enc3_w = (const float*)d_in[6];
  const float* enc3_b = (const float*)d_in[7];
  const float* loc_w  = (const float*)d_in[8];
  const float* loc_b  = (const float*)d_in[9];
  const float* glob_w = (const float*)d_in[10];
  const float* glob_b = (const float*)d_in[11];
  const float* d1w    = (const float*)d_in[12];
  const float* d1b    = (const float*)d_in[13];
  const float* d2w    = (const float*)d_in[14];
  const float* d2b    = (const float*)d_in[15];
  const float* d3w    = (const float*)d_in[16];
  const float* d3b    = (const float*)d_in[17];
  float* out = (float*)d_out;

  // workspace layout (bytes, 256B-aligned)
  char* ws = (char*)d_ws;
  size_t o = 0;
  __hip_bfloat16* xb = (__hip_bfloat16*)(ws + o); o += 8388608;     // N*128 bf16
  int*   ai    = (int*)  (ws + o); o += 4194304;                    // N*32 i32
  int*   cnt   = (int*)  (ws + o); o += 131072;
  int*   invwi = (int*)  (ws + o); o += 131072;
  float* Macc  = (float*)(ws + o); o += 17408;                      // MROW padded
  float* w2T   = (float*)(ws + o); o += 16384;
  float* w3T   = (float*)(ws + o); o += 32768;
  float* locT  = (float*)(ws + o); o += 134144;
  float* globT = (float*)(ws + o); o += 393216;
  float* d1T   = (float*)(ws + o); o += 393216;
  float* d2T   = (float*)(ws + o); o += 131072;
  float* d3T   = (float*)(ws + o); o += 8192;
  float* partial = (float*)(ws + o);                                // NBLK*MROW f32
  (void)ws_size;

  hipMemsetAsync(cnt, 0, NPTS * sizeof(int), stream);
  hipMemsetAsync(ai, 0, NPTS * 32 * sizeof(int), stream);

  prep_kernel<<<1083, 256, 0, stream>>>(enc2_w, enc3_w, loc_w, glob_w, d1w, d2w, d3w,
                                        w2T, w3T, locT, globT, d1T, d2T, d3T);
  hist_kernel<<<EEDGES / 1024, 256, 0, stream>>>(ei, cnt);
  invwi_kernel<<<NPTS / 256, 256, 0, stream>>>(cnt, invwi, ai);
  enc_kernel<<<NPTS / 128, 128, 0, stream>>>(pos, enc1_w, enc1_b, w2T, enc2_b,
                                             w3T, enc3_b, xb);
  ascatter_kernel<<<EEDGES / 256, 256, 0, stream>>>(ei, invwi, ai);
  contract_kernel<<<NBLK, 256, 0, stream>>>((const ushort*)xb, pos, ai, partial);
  reduce_kernel<<<MROW / 4, 256, 0, stream>>>(partial, Macc);
  final_kernel<<<NCLOUD, 256, 0, stream>>>(Macc, pos, locT, loc_b, globT, glob_b,
                                           d1T, d1b, d2T, d2b, d3T, d3b, out);
}

// Round 7
// 288.600 us; speedup vs baseline: 2.2351x; 2.2351x over previous
//
#include <hip/hip_runtime.h>
#include <hip/hip_bf16.h>

#define NPTS   32768
#define EEDGES 1048576
#define PTSC   1024
#define NCLOUD 32
#define ADIM   132              // per-cloud stride: 128 x + 3 pos + pad
#define MROW   (NCLOUD * ADIM)  // 4224
#define NBLK   256              // contract partial blocks
#define CHUNK  (NPTS / NBLK)    // 128
#define FXSCALE 16777216.0f     // 2^24

// ---------------- weight transpose prep: dst[c*R + r] = src[r*C + c] ----------------
__global__ __launch_bounds__(256) void prep_kernel(
    const float* __restrict__ w2, const float* __restrict__ w3,
    const float* __restrict__ locw, const float* __restrict__ globw,
    const float* __restrict__ d1w, const float* __restrict__ d2w,
    const float* __restrict__ d3w,
    float* __restrict__ w2T, float* __restrict__ w3T,
    float* __restrict__ locT, float* __restrict__ globT,
    float* __restrict__ d1T, float* __restrict__ d2T, float* __restrict__ d3T) {
  int idx = blockIdx.x * 256 + threadIdx.x;
  const float* src; float* dst; int R, C;
  if (idx < 4096)        { src = w2;   dst = w2T;   R = 64;  C = 64;  }
  else if (idx < 12288)  { src = w3;   dst = w3T;   R = 128; C = 64;  idx -= 4096; }
  else if (idx < 45824)  { src = locw; dst = locT;  R = 256; C = 131; idx -= 12288; }
  else if (idx < 144128) { src = globw;dst = globT; R = 384; C = 256; idx -= 45824; }
  else if (idx < 242432) { src = d1w;  dst = d1T;   R = 256; C = 384; idx -= 144128; }
  else if (idx < 275200) { src = d2w;  dst = d2T;   R = 128; C = 256; idx -= 242432; }
  else                   { src = d3w;  dst = d3T;   R = 16;  C = 128; idx -= 275200; }
  int c = idx / R, r = idx % R;
  dst[idx] = src[r * C + c];
}

__device__ __forceinline__ unsigned pack_bf16(float a, float b) {
  __hip_bfloat162 o;
  o.x = __float2bfloat16(a);
  o.y = __float2bfloat16(b);
  return *reinterpret_cast<unsigned*>(&o);
}

// ---------------- encoder: 4 pts/wave, weights in registers, readlane broadcasts ----------------
// lane owns layer1/2 row `lane`, layer3 rows 2*lane, 2*lane+1.
__global__ __launch_bounds__(256) void enc_kernel(
    const float* __restrict__ pos,
    const float* __restrict__ w1, const float* __restrict__ b1,
    const float* __restrict__ w2T, const float* __restrict__ b2,
    const float* __restrict__ w3T, const float* __restrict__ b3,
    __hip_bfloat16* __restrict__ xb) {
  int wid  = (blockIdx.x * blockDim.x + threadIdx.x) >> 6;
  int lane = threadIdx.x & 63;
  int i0 = wid * 4;
  if (i0 >= NPTS) return;

  // ---- preload weights into registers (coalesced, once per wave) ----
  float w2r[64];                       // w2 row `lane`
#pragma unroll
  for (int k = 0; k < 64; ++k) w2r[k] = w2T[k * 64 + lane];
  int r0 = 2 * lane;
  float w3a[64], w3b[64];              // w3 rows r0, r0+1
#pragma unroll
  for (int k = 0; k < 64; ++k) {
    float2 w = *reinterpret_cast<const float2*>(w3T + k * 128 + r0);
    w3a[k] = w.x; w3b[k] = w.y;
  }

  float w1a = w1[lane * 3 + 0], w1b = w1[lane * 3 + 1], w1c = w1[lane * 3 + 2];
  float bb1 = b1[lane];

  float h1[4];
#pragma unroll
  for (int p = 0; p < 4; ++p) {
    int i = i0 + p;
    float px = pos[i * 3 + 0], py = pos[i * 3 + 1], pz = pos[i * 3 + 2];
    h1[p] = tanhf(w1a * px + w1b * py + w1c * pz + bb1);
  }

  float bb2 = b2[lane];
  float acc2[4] = {bb2, bb2, bb2, bb2};
#pragma unroll
  for (int k = 0; k < 64; ++k) {       // full unroll -> __shfl(_,k) becomes v_readlane
    float w = w2r[k];
#pragma unroll
    for (int p = 0; p < 4; ++p) acc2[p] += w * __shfl(h1[p], k);
  }
  float h2[4];
#pragma unroll
  for (int p = 0; p < 4; ++p) h2[p] = tanhf(acc2[p]);

  float bb3a = b3[r0], bb3b = b3[r0 + 1];
  float acc3a[4] = {bb3a, bb3a, bb3a, bb3a};
  float acc3b[4] = {bb3b, bb3b, bb3b, bb3b};
#pragma unroll
  for (int k = 0; k < 64; ++k) {
    float wa = w3a[k], wb = w3b[k];
#pragma unroll
    for (int p = 0; p < 4; ++p) {
      float h = __shfl(h2[p], k);
      acc3a[p] += wa * h;
      acc3b[p] += wb * h;
    }
  }
#pragma unroll
  for (int p = 0; p < 4; ++p) {
    int i = i0 + p;
    unsigned o = pack_bf16(tanhf(acc3a[p]), tanhf(acc3b[p]));
    *reinterpret_cast<unsigned*>(xb + (size_t)i * 128 + r0) = o;
  }
}

// ---------------- degree histogram ----------------
__global__ __launch_bounds__(256) void hist_kernel(const int* __restrict__ ei,
                                                   int* __restrict__ cnt) {
  int t = blockIdx.x * 256 + threadIdx.x;
  const int4* d4 = reinterpret_cast<const int4*>(ei + EEDGES);
  int4 v = d4[t];
  atomicAdd(&cnt[v.x], 1);
  atomicAdd(&cnt[v.y], 1);
  atomicAdd(&cnt[v.z], 1);
  atomicAdd(&cnt[v.w], 1);
}

// invwi + self-loop diagonal store (after ai memset, before ascatter atomics)
__global__ __launch_bounds__(256) void invwi_kernel(const int* __restrict__ cnt,
                                                    int* __restrict__ invwi,
                                                    int* __restrict__ ai) {
  int i = blockIdx.x * 256 + threadIdx.x;
  if (i < NPTS) {
    int v = (int)rintf(FXSCALE / (float)(cnt[i] + 1));
    invwi[i] = v;
    ai[i * 32 + (i >> 10)] = v;   // self-loop contribution
  }
}

// ---------------- alpha scatter (edges only) ----------------
__global__ __launch_bounds__(256) void ascatter_kernel(const int* __restrict__ ei,
                                                       const int* __restrict__ invwi,
                                                       int* __restrict__ ai) {
  int e = blockIdx.x * 256 + threadIdx.x;
  int s = ei[e];
  int d = ei[e + EEDGES];
  atomicAdd(&ai[s * 32 + (d >> 10)], invwi[d]);
}

// ---------------- contraction: partial[b][c][dim] = sum_s alpha[s][c]*X[s][dim] ----------------
__global__ __launch_bounds__(256) void contract_kernel(
    const ushort* __restrict__ xu, const float* __restrict__ pos,
    const int* __restrict__ ai, float* __restrict__ partial) {
  int w = threadIdx.x >> 6, l = threadIdx.x & 63;
  int cw = w * 8;
  int s0 = blockIdx.x * CHUNK;
  int s1 = s0 + CHUNK;

  float a0[8] = {0,0,0,0,0,0,0,0};
  float a1[8] = {0,0,0,0,0,0,0,0};
  float a2[8] = {0,0,0,0,0,0,0,0};

#pragma unroll 2
  for (int s = s0; s < s1; ++s) {
    unsigned xr = *reinterpret_cast<const unsigned*>(xu + (size_t)s * 128 + 2 * l);
    float f0 = __uint_as_float(xr << 16);
    float f1 = __uint_as_float(xr & 0xffff0000u);
    float p  = (l < 3) ? pos[s * 3 + l] : 0.f;
    const int4* ar = reinterpret_cast<const int4*>(ai + (size_t)s * 32 + cw);
    int4 A0 = ar[0], A1 = ar[1];
    float af[8] = {(float)A0.x, (float)A0.y, (float)A0.z, (float)A0.w,
                   (float)A1.x, (float)A1.y, (float)A1.z, (float)A1.w};
#pragma unroll
    for (int cc = 0; cc < 8; ++cc) {
      a0[cc] += af[cc] * f0;
      a1[cc] += af[cc] * f1;
      a2[cc] += af[cc] * p;
    }
  }

  const float SC = 1.0f / FXSCALE;
  float* pb = partial + (size_t)blockIdx.x * MROW;
#pragma unroll
  for (int cc = 0; cc < 8; ++cc) {
    pb[(cw + cc) * ADIM + 2 * l]     = a0[cc] * SC;
    pb[(cw + cc) * ADIM + 2 * l + 1] = a1[cc] * SC;
    if (l < 3) pb[(cw + cc) * ADIM + 128 + l] = a2[cc] * SC;
  }
}

// ---------------- reduce: one wave per idx, shfl tree ----------------
__global__ __launch_bounds__(256) void reduce_kernel(const float* __restrict__ partial,
                                                     float* __restrict__ Macc) {
  int w = threadIdx.x >> 6, l = threadIdx.x & 63;
  int idx = blockIdx.x * 4 + w;
  if (idx >= MROW) return;
  float s = 0.f;
#pragma unroll
  for (int b = 0; b < NBLK; b += 64)
    s += partial[(size_t)(b + l) * MROW + idx];
  s += __shfl_xor(s, 32);
  s += __shfl_xor(s, 16);
  s += __shfl_xor(s, 8);
  s += __shfl_xor(s, 4);
  s += __shfl_xor(s, 2);
  s += __shfl_xor(s, 1);
  if (l == 0) Macc[idx] = s;
}

// ---------------- tail MLP (transposed weights, coalesced) ----------------
__global__ __launch_bounds__(256) void final_kernel(
    const float* __restrict__ Macc, const float* __restrict__ pos,
    const float* __restrict__ locT, const float* __restrict__ loc_b,
    const float* __restrict__ globT, const float* __restrict__ glob_b,
    const float* __restrict__ d1T, const float* __restrict__ d1b,
    const float* __restrict__ d2T, const float* __restrict__ d2b,
    const float* __restrict__ d3T, const float* __restrict__ d3b,
    float* __restrict__ out) {
  int c = blockIdx.x, t = threadIdx.x;
  __shared__ float red[3][256];
  __shared__ float m[131];
  __shared__ float tt[256];
  __shared__ float u[384];
  __shared__ float a[256];
  __shared__ float bv[128];

  float s0 = 0.f, s1 = 0.f, s2 = 0.f;
  for (int i = t; i < PTSC; i += 256) {
    const float* pr = pos + ((size_t)c * PTSC + i) * 3;
    s0 += pr[0]; s1 += pr[1]; s2 += pr[2];
  }
  red[0][t] = s0; red[1][t] = s1; red[2][t] = s2;
  __syncthreads();
  for (int off = 128; off > 0; off >>= 1) {
    if (t < off) {
      red[0][t] += red[0][t + off];
      red[1][t] += red[1][t + off];
      red[2][t] += red[2][t + off];
    }
    __syncthreads();
  }

  if (t < 128)      m[t] = Macc[c * ADIM + t] * (1.0f / (float)PTSC);
  else if (t < 131) m[t] = (Macc[c * ADIM + t] - red[t - 128][0]) * (1.0f / (float)PTSC);
  __syncthreads();

  {
    float acc = loc_b[t];
    for (int k = 0; k < 131; ++k) acc += locT[k * 256 + t] * m[k];
    tt[t] = acc;
  }
  __syncthreads();

  for (int j = t; j < 384; j += 256) {
    float acc = glob_b[j];
    for (int k = 0; k < 256; ++k) acc += globT[k * 384 + j] * tt[k];
    u[j] = acc;
  }
  __syncthreads();

  {
    float acc = d1b[t];
    for (int k = 0; k < 384; ++k) acc += d1T[k * 256 + t] * u[k];
    a[t] = tanhf(acc);
  }
  __syncthreads();

  if (t < 128) {
    float acc = d2b[t];
    for (int k = 0; k < 256; ++k) acc += d2T[k * 128 + t] * a[k];
    bv[t] = tanhf(acc);
  }
  __syncthreads();

  if (t < 16) {
    float acc = d3b[t];
    for (int k = 0; k < 128; ++k) acc += d3T[k * 16 + t] * bv[k];
    out[c * 16 + t] = acc;
  }
}

extern "C" void kernel_launch(void* const* d_in, const int* in_sizes, int n_in,
                              void* d_out, int out_size, void* d_ws, size_t ws_size,
                              hipStream_t stream) {
  const float* pos    = (const float*)d_in[0];
  const int*   ei     = (const int*)d_in[1];
  const float* enc1_w = (const float*)d_in[2];
  const float* enc1_b = (const float*)d_in[3];
  const float* enc2_w = (const float*)d_in[4];
  const float* enc2_b = (const float*)d_in[5];
  const float* enc3_w = (const float*)d_in[6];
  const float* enc3_b = (const float*)d_in[7];
  const float* loc_w  = (const float*)d_in[8];
  const float* loc_b  = (const float*)d_in[9];
  const float* glob_w = (const float*)d_in[10];
  const float* glob_b = (const float*)d_in[11];
  const float* d1w    = (const float*)d_in[12];
  const float* d1b    = (const float*)d_in[13];
  const float* d2w    = (const float*)d_in[14];
  const float* d2b    = (const float*)d_in[15];
  const float* d3w    = (const float*)d_in[16];
  const float* d3b    = (const float*)d_in[17];
  float* out = (float*)d_out;

  // workspace layout (bytes, 256B-aligned)
  char* ws = (char*)d_ws;
  size_t o = 0;
  __hip_bfloat16* xb = (__hip_bfloat16*)(ws + o); o += 8388608;     // N*128 bf16
  int*   ai    = (int*)  (ws + o); o += 4194304;                    // N*32 i32
  int*   cnt   = (int*)  (ws + o); o += 131072;
  int*   invwi = (int*)  (ws + o); o += 131072;
  float* Macc  = (float*)(ws + o); o += 17408;                      // MROW padded
  float* w2T   = (float*)(ws + o); o += 16384;
  float* w3T   = (float*)(ws + o); o += 32768;
  float* locT  = (float*)(ws + o); o += 134144;
  float* globT = (float*)(ws + o); o += 393216;
  float* d1T   = (float*)(ws + o); o += 393216;
  float* d2T   = (float*)(ws + o); o += 131072;
  float* d3T   = (float*)(ws + o); o += 8192;
  float* partial = (float*)(ws + o);                                // NBLK*MROW f32
  (void)ws_size;

  hipMemsetAsync(cnt, 0, NPTS * sizeof(int), stream);
  hipMemsetAsync(ai, 0, NPTS * 32 * sizeof(int), stream);

  prep_kernel<<<1083, 256, 0, stream>>>(enc2_w, enc3_w, loc_w, glob_w, d1w, d2w, d3w,
                                        w2T, w3T, locT, globT, d1T, d2T, d3T);
  hist_kernel<<<EEDGES / 1024, 256, 0, stream>>>(ei, cnt);
  invwi_kernel<<<NPTS / 256, 256, 0, stream>>>(cnt, invwi, ai);
  enc_kernel<<<NPTS / 16, 256, 0, stream>>>(pos, enc1_w, enc1_b, w2T, enc2_b,
                                            w3T, enc3_b, xb);
  ascatter_kernel<<<EEDGES / 256, 256, 0, stream>>>(ei, invwi, ai);
  contract_kernel<<<NBLK, 256, 0, stream>>>((const ushort*)xb, pos, ai, partial);
  reduce_kernel<<<MROW / 4, 256, 0, stream>>>(partial, Macc);
  final_kernel<<<NCLOUD, 256, 0, stream>>>(Macc, pos, locT, loc_b, globT, glob_b,
                                           d1T, d1b, d2T, d2b, d3T, d3b, out);
}

// Round 8
// 236.922 us; speedup vs baseline: 2.7226x; 1.2181x over previous
//
#include <hip/hip_runtime.h>
#include <hip/hip_bf16.h>

#define NPTS   32768
#define EEDGES 1048576
#define PTSC   1024
#define NCLOUD 32
#define ADIM   132              // per-cloud stride: 128 x + 3 pos + pad
#define MROW   (NCLOUD * ADIM)  // 4224
#define NBLK   256              // contract partial blocks
#define CHUNK  (NPTS / NBLK)    // 128
#define FXSCALE 16777216.0f     // 2^24

// ---------------- weight transpose prep: dst[c*R + r] = src[r*C + c] ----------------
__global__ __launch_bounds__(256) void prep_kernel(
    const float* __restrict__ w2, const float* __restrict__ w3,
    const float* __restrict__ locw, const float* __restrict__ globw,
    const float* __restrict__ d1w, const float* __restrict__ d2w,
    const float* __restrict__ d3w,
    float* __restrict__ w2T, float* __restrict__ w3T,
    float* __restrict__ locT, float* __restrict__ globT,
    float* __restrict__ d1T, float* __restrict__ d2T, float* __restrict__ d3T) {
  int idx = blockIdx.x * 256 + threadIdx.x;
  const float* src; float* dst; int R, C;
  if (idx < 4096)        { src = w2;   dst = w2T;   R = 64;  C = 64;  }
  else if (idx < 12288)  { src = w3;   dst = w3T;   R = 128; C = 64;  idx -= 4096; }
  else if (idx < 45824)  { src = locw; dst = locT;  R = 256; C = 131; idx -= 12288; }
  else if (idx < 144128) { src = globw;dst = globT; R = 384; C = 256; idx -= 45824; }
  else if (idx < 242432) { src = d1w;  dst = d1T;   R = 256; C = 384; idx -= 144128; }
  else if (idx < 275200) { src = d2w;  dst = d2T;   R = 128; C = 256; idx -= 242432; }
  else                   { src = d3w;  dst = d3T;   R = 16;  C = 128; idx -= 275200; }
  int c = idx / R, r = idx % R;
  dst[idx] = src[r * C + c];
}

__device__ __forceinline__ unsigned pack_bf16(float a, float b) {
  __hip_bfloat162 o;
  o.x = __float2bfloat16(a);
  o.y = __float2bfloat16(b);
  return *reinterpret_cast<unsigned*>(&o);
}

__device__ __forceinline__ float rlane(float x, int k) {
  return __int_as_float(__builtin_amdgcn_readlane(__float_as_int(x), k));
}

// ---------------- encoder: 8 pts/wave, in-loop weight loads, readlane broadcasts ----
// lane owns layer1/2 row `lane`, layer3 rows 2*lane, 2*lane+1.
__global__ __launch_bounds__(256) void enc_kernel(
    const float* __restrict__ pos,
    const float* __restrict__ w1, const float* __restrict__ b1,
    const float* __restrict__ w2T, const float* __restrict__ b2,
    const float* __restrict__ w3T, const float* __restrict__ b3,
    __hip_bfloat16* __restrict__ xb) {
  int wid  = (blockIdx.x * blockDim.x + threadIdx.x) >> 6;
  int lane = threadIdx.x & 63;
  int i0 = __builtin_amdgcn_readfirstlane(wid * 8);   // wave-uniform point base

  float w1a = w1[lane * 3 + 0], w1b = w1[lane * 3 + 1], w1c = w1[lane * 3 + 2];
  float bb1 = b1[lane];

  float h1[8];
#pragma unroll
  for (int p = 0; p < 8; ++p) {
    int i = i0 + p;
    float px = pos[i * 3 + 0], py = pos[i * 3 + 1], pz = pos[i * 3 + 2];  // scalar loads
    h1[p] = tanhf(w1a * px + w1b * py + w1c * pz + bb1);
  }

  float bb2 = b2[lane];
  float acc2[8];
#pragma unroll
  for (int p = 0; p < 8; ++p) acc2[p] = bb2;
#pragma unroll
  for (int k = 0; k < 64; ++k) {
    float w = w2T[k * 64 + lane];               // coalesced, L1-resident
#pragma unroll
    for (int p = 0; p < 8; ++p) acc2[p] += w * rlane(h1[p], k);
  }
  float h2[8];
#pragma unroll
  for (int p = 0; p < 8; ++p) h2[p] = tanhf(acc2[p]);

  int r0 = 2 * lane;
  float bb3a = b3[r0], bb3b = b3[r0 + 1];
  float acc3a[8], acc3b[8];
#pragma unroll
  for (int p = 0; p < 8; ++p) { acc3a[p] = bb3a; acc3b[p] = bb3b; }
#pragma unroll
  for (int k = 0; k < 64; ++k) {
    float2 w = *reinterpret_cast<const float2*>(w3T + k * 128 + r0);  // coalesced
#pragma unroll
    for (int p = 0; p < 8; ++p) {
      float h = rlane(h2[p], k);
      acc3a[p] += w.x * h;
      acc3b[p] += w.y * h;
    }
  }
#pragma unroll
  for (int p = 0; p < 8; ++p) {
    int i = i0 + p;
    unsigned o = pack_bf16(tanhf(acc3a[p]), tanhf(acc3b[p]));
    *reinterpret_cast<unsigned*>(xb + (size_t)i * 128 + r0) = o;
  }
}

// ---------------- degree histogram ----------------
__global__ __launch_bounds__(256) void hist_kernel(const int* __restrict__ ei,
                                                   int* __restrict__ cnt) {
  int t = blockIdx.x * 256 + threadIdx.x;
  const int4* d4 = reinterpret_cast<const int4*>(ei + EEDGES);
  int4 v = d4[t];
  atomicAdd(&cnt[v.x], 1);
  atomicAdd(&cnt[v.y], 1);
  atomicAdd(&cnt[v.z], 1);
  atomicAdd(&cnt[v.w], 1);
}

// invwi + full alpha-row init (zeros + self-loop diagonal) — replaces ai memset
__global__ __launch_bounds__(256) void invwi_kernel(const int* __restrict__ cnt,
                                                    int* __restrict__ invwi,
                                                    int* __restrict__ ai) {
  int i = blockIdx.x * 256 + threadIdx.x;
  int v = (int)rintf(FXSCALE / (float)(cnt[i] + 1));
  invwi[i] = v;
  int4 z = make_int4(0, 0, 0, 0);
  int4* row = reinterpret_cast<int4*>(ai + i * 32);
#pragma unroll
  for (int q = 0; q < 8; ++q) row[q] = z;
  ai[i * 32 + (i >> 10)] = v;   // self-loop contribution
}

// ---------------- alpha scatter (edges only) ----------------
__global__ __launch_bounds__(256) void ascatter_kernel(const int* __restrict__ ei,
                                                       const int* __restrict__ invwi,
                                                       int* __restrict__ ai) {
  int e = blockIdx.x * 256 + threadIdx.x;
  int s = ei[e];
  int d = ei[e + EEDGES];
  atomicAdd(&ai[s * 32 + (d >> 10)], invwi[d]);
}

// ---------------- contraction: partial[b][c][dim] = sum_s alpha[s][c]*X[s][dim] ----------------
__global__ __launch_bounds__(256) void contract_kernel(
    const ushort* __restrict__ xu, const float* __restrict__ pos,
    const int* __restrict__ ai, float* __restrict__ partial) {
  int w = threadIdx.x >> 6, l = threadIdx.x & 63;
  int cw = w * 8;
  int s0 = blockIdx.x * CHUNK;
  int s1 = s0 + CHUNK;

  float a0[8] = {0,0,0,0,0,0,0,0};
  float a1[8] = {0,0,0,0,0,0,0,0};
  float a2[8] = {0,0,0,0,0,0,0,0};

#pragma unroll 2
  for (int s = s0; s < s1; ++s) {
    unsigned xr = *reinterpret_cast<const unsigned*>(xu + (size_t)s * 128 + 2 * l);
    float f0 = __uint_as_float(xr << 16);
    float f1 = __uint_as_float(xr & 0xffff0000u);
    float p  = (l < 3) ? pos[s * 3 + l] : 0.f;
    const int4* ar = reinterpret_cast<const int4*>(ai + (size_t)s * 32 + cw);
    int4 A0 = ar[0], A1 = ar[1];
    float af[8] = {(float)A0.x, (float)A0.y, (float)A0.z, (float)A0.w,
                   (float)A1.x, (float)A1.y, (float)A1.z, (float)A1.w};
#pragma unroll
    for (int cc = 0; cc < 8; ++cc) {
      a0[cc] += af[cc] * f0;
      a1[cc] += af[cc] * f1;
      a2[cc] += af[cc] * p;
    }
  }

  const float SC = 1.0f / FXSCALE;
  float* pb = partial + (size_t)blockIdx.x * MROW;
#pragma unroll
  for (int cc = 0; cc < 8; ++cc) {
    pb[(cw + cc) * ADIM + 2 * l]     = a0[cc] * SC;
    pb[(cw + cc) * ADIM + 2 * l + 1] = a1[cc] * SC;
    if (l < 3) pb[(cw + cc) * ADIM + 128 + l] = a2[cc] * SC;
  }
}

// ---------------- reduce: one wave per idx, shfl tree ----------------
__global__ __launch_bounds__(256) void reduce_kernel(const float* __restrict__ partial,
                                                     float* __restrict__ Macc) {
  int w = threadIdx.x >> 6, l = threadIdx.x & 63;
  int idx = blockIdx.x * 4 + w;
  if (idx >= MROW) return;
  float s = 0.f;
#pragma unroll
  for (int b = 0; b < NBLK; b += 64)
    s += partial[(size_t)(b + l) * MROW + idx];
  s += __shfl_xor(s, 32);
  s += __shfl_xor(s, 16);
  s += __shfl_xor(s, 8);
  s += __shfl_xor(s, 4);
  s += __shfl_xor(s, 2);
  s += __shfl_xor(s, 1);
  if (l == 0) Macc[idx] = s;
}

// ---------------- tail MLP (transposed weights, coalesced) ----------------
__global__ __launch_bounds__(256) void final_kernel(
    const float* __restrict__ Macc, const float* __restrict__ pos,
    const float* __restrict__ locT, const float* __restrict__ loc_b,
    const float* __restrict__ globT, const float* __restrict__ glob_b,
    const float* __restrict__ d1T, const float* __restrict__ d1b,
    const float* __restrict__ d2T, const float* __restrict__ d2b,
    const float* __restrict__ d3T, const float* __restrict__ d3b,
    float* __restrict__ out) {
  int c = blockIdx.x, t = threadIdx.x;
  __shared__ float red[3][256];
  __shared__ float m[131];
  __shared__ float tt[256];
  __shared__ float u[384];
  __shared__ float a[256];
  __shared__ float bv[128];

  float s0 = 0.f, s1 = 0.f, s2 = 0.f;
  for (int i = t; i < PTSC; i += 256) {
    const float* pr = pos + ((size_t)c * PTSC + i) * 3;
    s0 += pr[0]; s1 += pr[1]; s2 += pr[2];
  }
  red[0][t] = s0; red[1][t] = s1; red[2][t] = s2;
  __syncthreads();
  for (int off = 128; off > 0; off >>= 1) {
    if (t < off) {
      red[0][t] += red[0][t + off];
      red[1][t] += red[1][t + off];
      red[2][t] += red[2][t + off];
    }
    __syncthreads();
  }

  if (t < 128)      m[t] = Macc[c * ADIM + t] * (1.0f / (float)PTSC);
  else if (t < 131) m[t] = (Macc[c * ADIM + t] - red[t - 128][0]) * (1.0f / (float)PTSC);
  __syncthreads();

  {
    float acc = loc_b[t];
    for (int k = 0; k < 131; ++k) acc += locT[k * 256 + t] * m[k];
    tt[t] = acc;
  }
  __syncthreads();

  for (int j = t; j < 384; j += 256) {
    float acc = glob_b[j];
    for (int k = 0; k < 256; ++k) acc += globT[k * 384 + j] * tt[k];
    u[j] = acc;
  }
  __syncthreads();

  {
    float acc = d1b[t];
    for (int k = 0; k < 384; ++k) acc += d1T[k * 256 + t] * u[k];
    a[t] = tanhf(acc);
  }
  __syncthreads();

  if (t < 128) {
    float acc = d2b[t];
    for (int k = 0; k < 256; ++k) acc += d2T[k * 128 + t] * a[k];
    bv[t] = tanhf(acc);
  }
  __syncthreads();

  if (t < 16) {
    float acc = d3b[t];
    for (int k = 0; k < 128; ++k) acc += d3T[k * 16 + t] * bv[k];
    out[c * 16 + t] = acc;
  }
}

extern "C" void kernel_launch(void* const* d_in, const int* in_sizes, int n_in,
                              void* d_out, int out_size, void* d_ws, size_t ws_size,
                              hipStream_t stream) {
  const float* pos    = (const float*)d_in[0];
  const int*   ei     = (const int*)d_in[1];
  const float* enc1_w = (const float*)d_in[2];
  const float* enc1_b = (const float*)d_in[3];
  const float* enc2_w = (const float*)d_in[4];
  const float* enc2_b = (const float*)d_in[5];
  const float* enc3_w = (const float*)d_in[6];
  const float* enc3_b = (const float*)d_in[7];
  const float* loc_w  = (const float*)d_in[8];
  const float* loc_b  = (const float*)d_in[9];
  const float* glob_w = (const float*)d_in[10];
  const float* glob_b = (const float*)d_in[11];
  const float* d1w    = (const float*)d_in[12];
  const float* d1b    = (const float*)d_in[13];
  const float* d2w    = (const float*)d_in[14];
  const float* d2b    = (const float*)d_in[15];
  const float* d3w    = (const float*)d_in[16];
  const float* d3b    = (const float*)d_in[17];
  float* out = (float*)d_out;

  // workspace layout (bytes, 256B-aligned)
  char* ws = (char*)d_ws;
  size_t o = 0;
  __hip_bfloat16* xb = (__hip_bfloat16*)(ws + o); o += 8388608;     // N*128 bf16
  int*   ai    = (int*)  (ws + o); o += 4194304;                    // N*32 i32
  int*   cnt   = (int*)  (ws + o); o += 131072;
  int*   invwi = (int*)  (ws + o); o += 131072;
  float* Macc  = (float*)(ws + o); o += 17408;                      // MROW padded
  float* w2T   = (float*)(ws + o); o += 16384;
  float* w3T   = (float*)(ws + o); o += 32768;
  float* locT  = (float*)(ws + o); o += 134144;
  float* globT = (float*)(ws + o); o += 393216;
  float* d1T   = (float*)(ws + o); o += 393216;
  float* d2T   = (float*)(ws + o); o += 131072;
  float* d3T   = (float*)(ws + o); o += 8192;
  float* partial = (float*)(ws + o);                                // NBLK*MROW f32
  (void)ws_size;

  hipMemsetAsync(cnt, 0, NPTS * sizeof(int), stream);

  prep_kernel<<<1083, 256, 0, stream>>>(enc2_w, enc3_w, loc_w, glob_w, d1w, d2w, d3w,
                                        w2T, w3T, locT, globT, d1T, d2T, d3T);
  hist_kernel<<<EEDGES / 1024, 256, 0, stream>>>(ei, cnt);
  invwi_kernel<<<NPTS / 256, 256, 0, stream>>>(cnt, invwi, ai);
  enc_kernel<<<NPTS / 32, 256, 0, stream>>>(pos, enc1_w, enc1_b, w2T, enc2_b,
                                            w3T, enc3_b, xb);
  ascatter_kernel<<<EEDGES / 256, 256, 0, stream>>>(ei, invwi, ai);
  contract_kernel<<<NBLK, 256, 0, stream>>>((const ushort*)xb, pos, ai, partial);
  reduce_kernel<<<MROW / 4, 256, 0, stream>>>(partial, Macc);
  final_kernel<<<NCLOUD, 256, 0, stream>>>(Macc, pos, locT, loc_b, globT, glob_b,
                                           d1T, d1b, d2T, d2b, d3T, d3b, out);
}